// Round 8
// baseline (264.110 us; speedup 1.0000x reference)
//
#include <hip/hip_runtime.h>

#define BB 8
#define HH 256
#define WW 512
#define HW (HH * WW)          // 131072
#define NPIX (BB * HW)        // 1048576

#define TXI 64                // inner tile width
#define TYI 16                // inner tile height
#define HALO 4                // iterations fused per kernel
#define SX (TXI + 2 * HALO)   // 72 staged width
#define SY (TYI + 2 * HALO)   // 24 staged height
#define NST (SX * SY)         // 1728 staged pixels
#define NSTP 1792             // padded to 7*256 for exact-wave DMA
#define CW (SX - 2)           // 70 computed cols (sx 1..70)
#define CYMAX (SY - 2)        // 22 = last computed staged row
#define RPT 8                 // rows per thread (3 groups)
#define SYTOP (SY - 1)        // 23, clamp limit
#define NBLK (BB * (WW / TXI) * (HH / TYI))   // 1024

typedef _Float16 half8 __attribute__((ext_vector_type(8)));

#if defined(__has_builtin)
#  if __has_builtin(__builtin_amdgcn_global_load_lds)
#    define HAVE_GLDS 1
#  endif
#endif
#ifndef HAVE_GLDS
#  define HAVE_GLDS 0
#endif

#define GLOAD_LDS16(gp, lp) __builtin_amdgcn_global_load_lds( \
    (const __attribute__((address_space(1))) void*)(gp),      \
    (__attribute__((address_space(3))) void*)(lp), 16, 0, 0)

// ---------------------------------------------------------------- prep ----
// Writes PRE-HALOED tile-contiguous g: g_tiled[bid][idx] = |guidance| fp16
// channels-last at staged position idx (sy*SX+sx), zeros outside image and
// in the pad tail. Same bid->tile/batch mapping as fused_kernel. Also d0.
__global__ __launch_bounds__(256) void prep_kernel(
    const float* __restrict__ guidance,   // [B,8,H,W] NCHW fp32
    const float* __restrict__ blur,
    const float* __restrict__ sparse,
    half8* __restrict__ g_tiled,          // [NBLK][NSTP] fp16x8
    float* __restrict__ d0)               // [B,H,W]
{
    const int bid  = blockIdx.x;
    const int b    = bid & 7;
    const int tile = bid >> 3;
    const int X0   = (tile & 7) * TXI;
    const int Y0   = (tile >> 3) * TYI;
    const int t    = threadIdx.x;

    half8* gt = g_tiled + (size_t)bid * NSTP;

#pragma unroll
    for (int r = 0; r < 7; ++r) {
        const int idx = r * 256 + t;      // 0..1791
        half8 h;
#pragma unroll
        for (int c = 0; c < 8; ++c) h[c] = (_Float16)0.0f;
        if (idx < NST) {
            const int sy = idx / SX;
            const int sx = idx - sy * SX;
            const int gy = Y0 - HALO + sy;
            const int gx = X0 - HALO + sx;
            if ((unsigned)gy < HH && (unsigned)gx < WW) {
                const size_t base = ((size_t)(b * 8) * HH + gy) * WW + gx;
#pragma unroll
                for (int c = 0; c < 8; ++c)
                    h[c] = (_Float16)fabsf(guidance[base + (size_t)c * HW]);
            }
        }
        gt[idx] = h;
    }

    // d0 for this block's inner 64x16 pixels (no overlap between blocks)
#pragma unroll
    for (int r = 0; r < 4; ++r) {
        const int j  = r * 256 + t;       // 0..1023
        const int iy = j >> 6;
        const int ix = j & 63;
        const size_t q = ((size_t)b * HH + (Y0 + iy)) * WW + (X0 + ix);
        const float sp = sparse[q];
        d0[q] = (sp > 0.0f) ? sp : blur[q];
    }
}

// --------------------------------------------------------------- fused ----
// 4 diffusion iterations in LDS. g staged via global_load_lds DMA from the
// pre-haloed tile (no VGPR round-trip, no ds_writes, no bounds math).
// Outermost staged ring frozen at input d; computed region 70x22; inner
// 64x16 exact after 4 iterations. invw computed in-register from LDS g.
__global__ __launch_bounds__(256) void fused_kernel(
    const half8* __restrict__ g_tiled,    // [NBLK][NSTP] fp16x8
    const float* __restrict__ sparse,     // [B,H,W]
    const float* __restrict__ src,        // [B,H,W] d in
    float* __restrict__ dst)              // [B,H,W] d out
{
    __shared__ half8 g_lds8[NSTP];        // 28672 B (linear, DMA target)
    __shared__ float d_lds[NST];          //  6912 B

    const int t    = threadIdx.x;
    const int wid  = t >> 6;              // wave id (uniform per wave)
    const int bid  = blockIdx.x;
    const int b    = bid & 7;             // batch == XCD hint (stable)
    const int tile = bid >> 3;
    const int X0   = (tile & 7) * TXI;
    const int Y0   = (tile >> 3) * TYI;

    // ---- issue g DMA: 7 x 1KiB per wave, LDS base wave-uniform ----
    const half8* gt = g_tiled + (size_t)bid * NSTP;
#if HAVE_GLDS
    {
        const int wbase = wid * 64;
#pragma unroll
        for (int r = 0; r < 7; ++r) {
            const int i = r * 256 + wbase;            // wave-uniform chunk
            GLOAD_LDS16(gt + i + (t & 63), (char*)g_lds8 + (size_t)i * 16);
        }
    }
#else
#pragma unroll
    for (int r = 0; r < 7; ++r) g_lds8[r * 256 + t] = gt[r * 256 + t];
#endif

    // ---- stage d (manual, bounds-checked) — overlaps with g DMA ----
    for (int idx = t; idx < NST; idx += 256) {
        const int sy = idx / SX;
        const int sx = idx - sy * SX;
        const int gy = Y0 - HALO + sy;
        const int gx = X0 - HALO + sx;
        float dv = 0.0f;
        if ((unsigned)gy < HH && (unsigned)gx < WW)
            dv = src[((size_t)b * HH + gy) * WW + gx];
        d_lds[idx] = dv;
    }

    // ---- per-thread pixel strip: column sxc, rows syB..syB+RPT-1 ----
    const int col = t % CW;               // 0..69
    const int grp = t / CW;               // 0..2 compute, 3 mostly idle
    const int sxc = 1 + col;
    const int syB = 1 + grp * RPT;

    unsigned vmask = 0;
#pragma unroll
    for (int k = 0; k < RPT; ++k) {
        const int sy = syB + k;
        const int gy = Y0 - HALO + sy;
        const int gx = X0 - HALO + sxc;
        if (grp < 3 && sy <= CYMAX && (unsigned)gy < HH && (unsigned)gx < WW)
            vmask |= (1u << k);
    }

    // ---- sparse values (issued before barrier: latency hidden) ----
    float spv[RPT];
#pragma unroll
    for (int k = 0; k < RPT; ++k) {
        spv[k] = 0.0f;
        if ((vmask >> k) & 1u) {
            const int gy = Y0 - HALO + syB + k;
            const int gx = X0 - HALO + sxc;
            spv[k] = sparse[((size_t)b * HH + gy) * WW + gx];
        }
    }

    __syncthreads();   // drains DMA (vmcnt) + d_lds writes (lgkmcnt)

    // ---- winv from LDS g (rolling row sums of g) ----
    half8 winv[RPT];
    {
        float gs[3][8];
        const int r0 = (syB - 1 < SYTOP) ? (syB - 1) : SYTOP;
        const int r1 = (syB     < SYTOP) ? syB       : SYTOP;
#pragma unroll
        for (int c = 0; c < 8; ++c) { gs[0][c] = 0.0f; gs[1][c] = 0.0f; }
#pragma unroll
        for (int dx = 0; dx < 3; ++dx) {
            const half8 ga = g_lds8[r0 * SX + sxc - 1 + dx];
            const half8 gb = g_lds8[r1 * SX + sxc - 1 + dx];
#pragma unroll
            for (int c = 0; c < 8; ++c) {
                gs[0][c] += (float)ga[c];
                gs[1][c] += (float)gb[c];
            }
        }
#pragma unroll
        for (int k = 0; k < RPT; ++k) {
            const int rn = syB + 1 + k;
            const int rc = (rn < SYTOP) ? rn : SYTOP;
            float* gn = gs[(2 + k) % 3];
#pragma unroll
            for (int c = 0; c < 8; ++c) gn[c] = 0.0f;
#pragma unroll
            for (int dx = 0; dx < 3; ++dx) {
                const half8 gh = g_lds8[rc * SX + sxc - 1 + dx];
#pragma unroll
                for (int c = 0; c < 8; ++c) gn[c] += (float)gh[c];
            }
            const int ia = k % 3, ib = (k + 1) % 3, ic = (k + 2) % 3;
#pragma unroll
            for (int c = 0; c < 8; ++c) {
                const float ws = gs[ia][c] + gs[ib][c] + gs[ic][c];
                winv[k][c] = (_Float16)(1.0f / ws);
            }
        }
    }

    // ---- 4 in-LDS iterations ----
    float dnew[RPT];
#pragma unroll
    for (int k = 0; k < RPT; ++k) dnew[k] = 0.0f;

#pragma unroll 1
    for (int it = 0; it < HALO; ++it) {
        float rs[3][8];
        {
            const int r0 = (syB - 1 < SYTOP) ? (syB - 1) : SYTOP;
            const int r1 = (syB     < SYTOP) ? syB       : SYTOP;
#pragma unroll
            for (int c = 0; c < 8; ++c) { rs[0][c] = 0.0f; rs[1][c] = 0.0f; }
#pragma unroll
            for (int dx = 0; dx < 3; ++dx) {
                const half8 ga = g_lds8[r0 * SX + sxc - 1 + dx];
                const float da = d_lds[r0 * SX + sxc - 1 + dx];
                const half8 gb = g_lds8[r1 * SX + sxc - 1 + dx];
                const float db = d_lds[r1 * SX + sxc - 1 + dx];
#pragma unroll
                for (int c = 0; c < 8; ++c) {
                    rs[0][c] = fmaf((float)ga[c], da, rs[0][c]);
                    rs[1][c] = fmaf((float)gb[c], db, rs[1][c]);
                }
            }
        }
#pragma unroll
        for (int k = 0; k < RPT; ++k) {
            const int rn = syB + 1 + k;
            const int rc = (rn < SYTOP) ? rn : SYTOP;
            float* rsn = rs[(2 + k) % 3];
#pragma unroll
            for (int c = 0; c < 8; ++c) rsn[c] = 0.0f;
#pragma unroll
            for (int dx = 0; dx < 3; ++dx) {
                const half8 gh = g_lds8[rc * SX + sxc - 1 + dx];
                const float dv = d_lds[rc * SX + sxc - 1 + dx];
#pragma unroll
                for (int c = 0; c < 8; ++c)
                    rsn[c] = fmaf((float)gh[c], dv, rsn[c]);
            }
            const int ia = k % 3, ib = (k + 1) % 3, ic = (k + 2) % 3;
            float m = 0.0f;                       // candidates are >= 0
            const half8 w = winv[k];
#pragma unroll
            for (int c = 0; c < 8; ++c) {
                const float s = rs[ia][c] + rs[ib][c] + rs[ic][c];
                m = fmaxf(m, s * (float)w[c]);
            }
            dnew[k] = (spv[k] > 0.0f) ? spv[k] : m;
        }
        __syncthreads();                          // reads done
#pragma unroll
        for (int k = 0; k < RPT; ++k)
            if ((vmask >> k) & 1u) d_lds[(syB + k) * SX + sxc] = dnew[k];
        __syncthreads();                          // writes visible
    }

    // ---- write inner 64x16 tile ----
#pragma unroll
    for (int k = 0; k < RPT; ++k) {
        const int sy = syB + k;
        if (((vmask >> k) & 1u) && sxc >= HALO && sxc < HALO + TXI &&
            sy >= HALO && sy < HALO + TYI) {
            const int gy = Y0 - HALO + sy;
            const int gx = X0 - HALO + sxc;
            dst[((size_t)b * HH + gy) * WW + gx] = dnew[k];
        }
    }
}

// -------------------------------------------------------------- launch ----
extern "C" void kernel_launch(void* const* d_in, const int* in_sizes, int n_in,
                              void* d_out, int out_size, void* d_ws, size_t ws_size,
                              hipStream_t stream) {
    const float* guidance = (const float*)d_in[0];
    const float* blur     = (const float*)d_in[1];
    const float* sparse   = (const float*)d_in[2];
    float* out = (float*)d_out;

    half8* g_tiled = (half8*)d_ws;                                  // 29.36 MB
    float* buf0 = (float*)((char*)d_ws + (size_t)NBLK * NSTP * 16); // 4 MB
    float* buf1 = buf0 + (size_t)NPIX;                              // 4 MB

    prep_kernel<<<NBLK, 256, 0, stream>>>(guidance, blur, sparse, g_tiled, buf0);

    fused_kernel<<<NBLK, 256, 0, stream>>>(g_tiled, sparse, buf0, buf1);
    fused_kernel<<<NBLK, 256, 0, stream>>>(g_tiled, sparse, buf1, buf0);
    fused_kernel<<<NBLK, 256, 0, stream>>>(g_tiled, sparse, buf0, buf1);
    fused_kernel<<<NBLK, 256, 0, stream>>>(g_tiled, sparse, buf1, out);
}

// Round 9
// 256.947 us; speedup vs baseline: 1.0279x; 1.0279x over previous
//
#include <hip/hip_runtime.h>

#define BB 8
#define HH 256
#define WW 512
#define HW (HH * WW)          // 131072
#define NPIX (BB * HW)        // 1048576

#define TXI 64                // inner tile width
#define TYI 16                // inner tile height
#define HALO 4                // iterations fused per kernel
#define SX (TXI + 2 * HALO)   // 72 staged width
#define SY (TYI + 2 * HALO)   // 24 staged height
#define NST (SX * SY)         // 1728 staged pixels = 27 * 64 exactly
#define NCHUNK (NST / 64)     // 27 DMA chunks
#define CW (SX - 2)           // 70 computed cols (sx 1..70)
#define CYMAX (SY - 2)        // 22 = last computed staged row
#define RPT 8                 // rows per thread (3 groups)
#define SYTOP (SY - 1)        // 23, clamp limit
#define NBLK (BB * (WW / TXI) * (HH / TYI))   // 1024

typedef _Float16 half8 __attribute__((ext_vector_type(8)));

#if defined(__has_builtin)
#  if __has_builtin(__builtin_amdgcn_global_load_lds)
#    define HAVE_GLDS 1
#  endif
#endif
#ifndef HAVE_GLDS
#  define HAVE_GLDS 0
#endif

#define GLOAD_LDS16(gp, lp) __builtin_amdgcn_global_load_lds( \
    (const __attribute__((address_space(1))) void*)(gp),      \
    (__attribute__((address_space(3))) void*)(lp), 16, 0, 0)

// ---------------------------------------------------------------- prep ----
// Compact channels-last g (no halo redundancy — round 8's pre-haloed buffer
// doubled prep traffic). g_cl = |guidance| fp16; d0 = sparse>0?sparse:blur.
__global__ __launch_bounds__(256) void prep_kernel(
    const float* __restrict__ guidance,   // [B,8,H,W] NCHW fp32
    const float* __restrict__ blur,
    const float* __restrict__ sparse,
    half8* __restrict__ g_cl,             // [B,H,W,8] fp16
    float* __restrict__ d0)               // [B,H,W]
{
    const int bid = blockIdx.x;
    const int b   = bid & 7;
    const int p   = (bid >> 3) * 256 + threadIdx.x;   // 0..HW-1
    const int idx = b * HW + p;
    const size_t gbase = ((size_t)b * 8) * HW + p;

    half8 h;
#pragma unroll
    for (int c = 0; c < 8; ++c)
        h[c] = (_Float16)fabsf(guidance[gbase + (size_t)c * HW]);
    g_cl[idx] = h;

    const float sp = sparse[idx];
    d0[idx] = (sp > 0.0f) ? sp : blur[idx];
}

// --------------------------------------------------------------- fused ----
// 4 diffusion iterations in LDS. Interior blocks stage g via global_load_lds
// DMA straight from the COMPACT g_cl: LDS dest linear (chunk*1024 + lane*16),
// global source per-lane (row=i/72, col=i%72 mapped into [B,H,W,8]).
// Edge blocks (image border in halo) take the manual zero-filling path.
__global__ __launch_bounds__(256) void fused_kernel(
    const half8* __restrict__ g_cl,       // [B,H,W,8] fp16
    const float* __restrict__ sparse,     // [B,H,W]
    const float* __restrict__ src,        // [B,H,W] d in
    float* __restrict__ dst)              // [B,H,W] d out
{
    __shared__ half8 g_lds8[NST];         // 27648 B, linear [sy*SX+sx]
    __shared__ float d_lds[NST];          //  6912 B

    const int t    = threadIdx.x;
    const int lane = t & 63;
    const int wid  = t >> 6;              // wave id, uniform per wave
    const int bid  = blockIdx.x;
    const int b    = bid & 7;             // batch == XCD hint (stable)
    const int tile = bid >> 3;
    const int bx   = tile & 7;
    const int ty   = tile >> 3;
    const int X0   = bx * TXI;
    const int Y0   = ty * TYI;

    const bool interior = (bx > 0) & (bx < 7) & (ty > 0) & (ty < 15);

    if (interior) {
#if HAVE_GLDS
        // ---- DMA: 27 chunks of 64 lanes; per-lane global, linear LDS ----
#pragma unroll
        for (int r = 0; r < 7; ++r) {
            const int chunk = r * 4 + wid;            // uniform per wave
            if (chunk < NCHUNK) {
                const int i   = chunk * 64 + lane;    // 0..1727
                const int row = i / SX;
                const int col = i - row * SX;
                const int gy  = Y0 - HALO + row;
                const int gx  = X0 - HALO + col;
                const half8* gp = g_cl + ((size_t)b * HH + gy) * WW + gx;
                GLOAD_LDS16(gp, (char*)g_lds8 + (size_t)chunk * 1024);
            }
        }
#else
        for (int i = t; i < NST; i += 256) {
            const int row = i / SX;
            const int col = i - row * SX;
            const int gy  = Y0 - HALO + row;
            const int gx  = X0 - HALO + col;
            g_lds8[i] = g_cl[((size_t)b * HH + gy) * WW + gx];
        }
#endif
    } else {
        // ---- manual staging with zero fill outside the image ----
        for (int i = t; i < NST; i += 256) {
            const int row = i / SX;
            const int col = i - row * SX;
            const int gy  = Y0 - HALO + row;
            const int gx  = X0 - HALO + col;
            half8 h;
#pragma unroll
            for (int c = 0; c < 8; ++c) h[c] = (_Float16)0.0f;
            if ((unsigned)gy < HH && (unsigned)gx < WW)
                h = g_cl[((size_t)b * HH + gy) * WW + gx];
            g_lds8[i] = h;
        }
    }

    // ---- stage d (manual, bounds-checked) — overlaps with g DMA ----
    for (int i = t; i < NST; i += 256) {
        const int row = i / SX;
        const int col = i - row * SX;
        const int gy  = Y0 - HALO + row;
        const int gx  = X0 - HALO + col;
        float dv = 0.0f;
        if ((unsigned)gy < HH && (unsigned)gx < WW)
            dv = src[((size_t)b * HH + gy) * WW + gx];
        d_lds[i] = dv;
    }

    // ---- per-thread pixel strip: column sxc, rows syB..syB+RPT-1 ----
    const int col = t % CW;               // 0..69
    const int grp = t / CW;               // 0..2 compute, 3 mostly idle
    const int sxc = 1 + col;
    const int syB = 1 + grp * RPT;

    unsigned vmask = 0;
#pragma unroll
    for (int k = 0; k < RPT; ++k) {
        const int sy = syB + k;
        const int gy = Y0 - HALO + sy;
        const int gx = X0 - HALO + sxc;
        if (grp < 3 && sy <= CYMAX && (unsigned)gy < HH && (unsigned)gx < WW)
            vmask |= (1u << k);
    }

    // ---- sparse values (issued before barrier: latency hidden) ----
    float spv[RPT];
#pragma unroll
    for (int k = 0; k < RPT; ++k) {
        spv[k] = 0.0f;
        if ((vmask >> k) & 1u) {
            const int gy = Y0 - HALO + syB + k;
            const int gx = X0 - HALO + sxc;
            spv[k] = sparse[((size_t)b * HH + gy) * WW + gx];
        }
    }

    __syncthreads();   // drains DMA (vmcnt) + d_lds writes (lgkmcnt)

    // ---- winv from LDS g (rolling row sums of g) ----
    half8 winv[RPT];
    {
        float gs[3][8];
        const int r0 = (syB - 1 < SYTOP) ? (syB - 1) : SYTOP;
        const int r1 = (syB     < SYTOP) ? syB       : SYTOP;
#pragma unroll
        for (int c = 0; c < 8; ++c) { gs[0][c] = 0.0f; gs[1][c] = 0.0f; }
#pragma unroll
        for (int dx = 0; dx < 3; ++dx) {
            const half8 ga = g_lds8[r0 * SX + sxc - 1 + dx];
            const half8 gb = g_lds8[r1 * SX + sxc - 1 + dx];
#pragma unroll
            for (int c = 0; c < 8; ++c) {
                gs[0][c] += (float)ga[c];
                gs[1][c] += (float)gb[c];
            }
        }
#pragma unroll
        for (int k = 0; k < RPT; ++k) {
            const int rn = syB + 1 + k;
            const int rc = (rn < SYTOP) ? rn : SYTOP;
            float* gn = gs[(2 + k) % 3];
#pragma unroll
            for (int c = 0; c < 8; ++c) gn[c] = 0.0f;
#pragma unroll
            for (int dx = 0; dx < 3; ++dx) {
                const half8 gh = g_lds8[rc * SX + sxc - 1 + dx];
#pragma unroll
                for (int c = 0; c < 8; ++c) gn[c] += (float)gh[c];
            }
            const int ia = k % 3, ib = (k + 1) % 3, ic = (k + 2) % 3;
#pragma unroll
            for (int c = 0; c < 8; ++c) {
                const float ws = gs[ia][c] + gs[ib][c] + gs[ic][c];
                winv[k][c] = (_Float16)(1.0f / ws);
            }
        }
    }

    // ---- 4 in-LDS iterations ----
    float dnew[RPT];
#pragma unroll
    for (int k = 0; k < RPT; ++k) dnew[k] = 0.0f;

#pragma unroll 1
    for (int it = 0; it < HALO; ++it) {
        float rs[3][8];
        {
            const int r0 = (syB - 1 < SYTOP) ? (syB - 1) : SYTOP;
            const int r1 = (syB     < SYTOP) ? syB       : SYTOP;
#pragma unroll
            for (int c = 0; c < 8; ++c) { rs[0][c] = 0.0f; rs[1][c] = 0.0f; }
#pragma unroll
            for (int dx = 0; dx < 3; ++dx) {
                const half8 ga = g_lds8[r0 * SX + sxc - 1 + dx];
                const float da = d_lds[r0 * SX + sxc - 1 + dx];
                const half8 gb = g_lds8[r1 * SX + sxc - 1 + dx];
                const float db = d_lds[r1 * SX + sxc - 1 + dx];
#pragma unroll
                for (int c = 0; c < 8; ++c) {
                    rs[0][c] = fmaf((float)ga[c], da, rs[0][c]);
                    rs[1][c] = fmaf((float)gb[c], db, rs[1][c]);
                }
            }
        }
#pragma unroll
        for (int k = 0; k < RPT; ++k) {
            const int rn = syB + 1 + k;
            const int rc = (rn < SYTOP) ? rn : SYTOP;
            float* rsn = rs[(2 + k) % 3];
#pragma unroll
            for (int c = 0; c < 8; ++c) rsn[c] = 0.0f;
#pragma unroll
            for (int dx = 0; dx < 3; ++dx) {
                const half8 gh = g_lds8[rc * SX + sxc - 1 + dx];
                const float dv = d_lds[rc * SX + sxc - 1 + dx];
#pragma unroll
                for (int c = 0; c < 8; ++c)
                    rsn[c] = fmaf((float)gh[c], dv, rsn[c]);
            }
            const int ia = k % 3, ib = (k + 1) % 3, ic = (k + 2) % 3;
            float m = 0.0f;                       // candidates are >= 0
            const half8 w = winv[k];
#pragma unroll
            for (int c = 0; c < 8; ++c) {
                const float s = rs[ia][c] + rs[ib][c] + rs[ic][c];
                m = fmaxf(m, s * (float)w[c]);
            }
            dnew[k] = (spv[k] > 0.0f) ? spv[k] : m;
        }
        __syncthreads();                          // reads done
#pragma unroll
        for (int k = 0; k < RPT; ++k)
            if ((vmask >> k) & 1u) d_lds[(syB + k) * SX + sxc] = dnew[k];
        __syncthreads();                          // writes visible
    }

    // ---- write inner 64x16 tile ----
#pragma unroll
    for (int k = 0; k < RPT; ++k) {
        const int sy = syB + k;
        if (((vmask >> k) & 1u) && sxc >= HALO && sxc < HALO + TXI &&
            sy >= HALO && sy < HALO + TYI) {
            const int gy = Y0 - HALO + sy;
            const int gx = X0 - HALO + sxc;
            dst[((size_t)b * HH + gy) * WW + gx] = dnew[k];
        }
    }
}

// -------------------------------------------------------------- launch ----
extern "C" void kernel_launch(void* const* d_in, const int* in_sizes, int n_in,
                              void* d_out, int out_size, void* d_ws, size_t ws_size,
                              hipStream_t stream) {
    const float* guidance = (const float*)d_in[0];
    const float* blur     = (const float*)d_in[1];
    const float* sparse   = (const float*)d_in[2];
    float* out = (float*)d_out;

    half8* g_cl = (half8*)d_ws;                           // 16.78 MB
    float* buf0 = (float*)(g_cl + (size_t)NPIX);          // 4 MB
    float* buf1 = buf0 + (size_t)NPIX;                    // 4 MB

    prep_kernel<<<NPIX / 256, 256, 0, stream>>>(guidance, blur, sparse, g_cl, buf0);

    fused_kernel<<<NBLK, 256, 0, stream>>>(g_cl, sparse, buf0, buf1);
    fused_kernel<<<NBLK, 256, 0, stream>>>(g_cl, sparse, buf1, buf0);
    fused_kernel<<<NBLK, 256, 0, stream>>>(g_cl, sparse, buf0, buf1);
    fused_kernel<<<NBLK, 256, 0, stream>>>(g_cl, sparse, buf1, out);
}

// Round 10
// 189.280 us; speedup vs baseline: 1.3953x; 1.3575x over previous
//
#include <hip/hip_runtime.h>

#define BB 8
#define HH 256
#define WW 512
#define HW (HH * WW)          // 131072
#define NPIX (BB * HW)        // 1048576

#define TXI 64                // inner tile width
#define TYI 16                // inner tile height
#define HALO 4                // iterations fused per kernel
#define SX (TXI + 2 * HALO)   // 72 staged width
#define SY (TYI + 2 * HALO)   // 24 staged height
#define NST (SX * SY)         // 1728 staged pixels = 27 * 64
#define NCHUNK (NST / 64)     // 27 DMA chunks
#define CW (SX - 2)           // 70 computed cols
#define CYMAX (SY - 2)        // 22 = last computed staged row
#define RPT 8                 // rows per thread (3 groups)
#define SYTOP (SY - 1)        // 23, clamp limit
#define NBLK (BB * (WW / TXI) * (HH / TYI))   // 1024

#define PSX (TXI + 2)         // 66 prep staged width (1-halo)
#define PSY (TYI + 2)         // 18
#define PNST (PSX * PSY)      // 1188

typedef _Float16 half8 __attribute__((ext_vector_type(8)));

#if defined(__has_builtin)
#  if __has_builtin(__builtin_amdgcn_global_load_lds)
#    define HAVE_GLDS 1
#  endif
#endif
#ifndef HAVE_GLDS
#  define HAVE_GLDS 0
#endif

#define GLOAD_LDS16(gp, lp) __builtin_amdgcn_global_load_lds( \
    (const __attribute__((address_space(1))) void*)(gp),      \
    (__attribute__((address_space(3))) void*)(lp), 16, 0, 0)

// ---- v_fma_mix_f32: f32 acc += f16(half of g2) * f32 d — kills the cvt ----
__device__ __forceinline__ void fmixlo(float& a, unsigned g2, float d) {
    asm("v_fma_mix_f32 %0, %1, %2, %0 op_sel:[0,0,0] op_sel_hi:[1,0,0]"
        : "+v"(a) : "v"(g2), "v"(d));
}
__device__ __forceinline__ void fmixhi(float& a, unsigned g2, float d) {
    asm("v_fma_mix_f32 %0, %1, %2, %0 op_sel:[1,0,0] op_sel_hi:[1,0,0]"
        : "+v"(a) : "v"(g2), "v"(d));
}
__device__ __forceinline__ float mmixlo(unsigned w2, float s) {
    float r;
    asm("v_fma_mix_f32 %0, %1, %2, 0 op_sel:[0,0,0] op_sel_hi:[1,0,0]"
        : "=v"(r) : "v"(w2), "v"(s));
    return r;
}
__device__ __forceinline__ float mmixhi(unsigned w2, float s) {
    float r;
    asm("v_fma_mix_f32 %0, %1, %2, 0 op_sel:[1,0,0] op_sel_hi:[1,0,0]"
        : "=v"(r) : "v"(w2), "v"(s));
    return r;
}
// 8-channel FMA into rs[] from one packed half8 (as uint4) and one d scalar
__device__ __forceinline__ void rowfma(float (&rs)[8], uint4 gv, float dv) {
    fmixlo(rs[0], gv.x, dv); fmixhi(rs[1], gv.x, dv);
    fmixlo(rs[2], gv.y, dv); fmixhi(rs[3], gv.y, dv);
    fmixlo(rs[4], gv.z, dv); fmixhi(rs[5], gv.z, dv);
    fmixlo(rs[6], gv.w, dv); fmixhi(rs[7], gv.w, dv);
}

// ---------------------------------------------------------------- prep2 ----
// Merged prep + wsum, tiled. Stages |guidance| (fp16 CL) with 1-halo in LDS;
// writes compact g_cl, invw = fp16(1/wsum) (fp32 accumulation via fma_mix,
// from the ROUNDED fp16 g so numerics match the fused loop), and d0.
__global__ __launch_bounds__(256) void prep2_kernel(
    const float* __restrict__ guidance,   // [B,8,H,W] NCHW fp32
    const float* __restrict__ blur,
    const float* __restrict__ sparse,
    half8* __restrict__ g_cl,             // [B,H,W,8] fp16
    half8* __restrict__ invw,             // [B,H,W,8] fp16
    float* __restrict__ d0)               // [B,H,W]
{
    __shared__ half8 gp[PNST];            // 19008 B

    const int t    = threadIdx.x;
    const int bid  = blockIdx.x;
    const int b    = bid & 7;
    const int tile = bid >> 3;
    const int X0   = (tile & 7) * TXI;
    const int Y0   = (tile >> 3) * TYI;

    for (int i = t; i < PNST; i += 256) {
        const int sy = i / PSX;
        const int sx = i - sy * PSX;
        const int gy = Y0 - 1 + sy;
        const int gx = X0 - 1 + sx;
        half8 h;
#pragma unroll
        for (int c = 0; c < 8; ++c) h[c] = (_Float16)0.0f;
        if ((unsigned)gy < HH && (unsigned)gx < WW) {
            const size_t base = (size_t)(b * 8) * HW + gy * WW + gx;
#pragma unroll
            for (int c = 0; c < 8; ++c)
                h[c] = (_Float16)fabsf(guidance[base + (size_t)c * HW]);
            if (sy >= 1 && sy <= TYI && sx >= 1 && sx <= TXI)
                g_cl[((size_t)b * HH + gy) * WW + gx] = h;   // owner writes
        }
        gp[i] = h;
    }
    __syncthreads();

    const uint4* gpu = (const uint4*)gp;
    const float one = 1.0f;
#pragma unroll
    for (int r = 0; r < 4; ++r) {
        const int j  = r * 256 + t;       // 0..1023 inner px
        const int iy = j >> 6;
        const int ix = j & 63;
        float ws[8];
#pragma unroll
        for (int c = 0; c < 8; ++c) ws[c] = 0.0f;
#pragma unroll
        for (int ky = 0; ky < 3; ++ky)
#pragma unroll
            for (int kx = 0; kx < 3; ++kx)
                rowfma(ws, gpu[(iy + ky) * PSX + (ix + kx)], one);
        half8 w;
#pragma unroll
        for (int c = 0; c < 8; ++c)
            w[c] = (_Float16)__builtin_amdgcn_rcpf(ws[c]);
        const size_t q = ((size_t)b * HH + (Y0 + iy)) * WW + (X0 + ix);
        invw[q] = w;
        const float sp = sparse[q];
        d0[q] = (sp > 0.0f) ? sp : blur[q];
    }
}

// --------------------------------------------------------------- fused ----
// 4 diffusion iterations in LDS; g via DMA (interior) or manual (edge);
// invw LOADED (precomputed) during staging overlap; all inner-loop math via
// v_fma_mix_f32 (no f16->f32 converts). Frozen outer ring; inner 64x16
// exact after 4 iterations.
__global__ __launch_bounds__(256) void fused_kernel(
    const half8* __restrict__ g_cl,       // [B,H,W,8] fp16
    const half8* __restrict__ invw,       // [B,H,W,8] fp16
    const float* __restrict__ sparse,     // [B,H,W]
    const float* __restrict__ src,        // [B,H,W] d in
    float* __restrict__ dst)              // [B,H,W] d out
{
    __shared__ half8 g_lds8[NST];         // 27648 B, linear [sy*SX+sx]
    __shared__ float d_lds[NST];          //  6912 B

    const int t    = threadIdx.x;
    const int lane = t & 63;
    const int wid  = t >> 6;
    const int bid  = blockIdx.x;
    const int b    = bid & 7;             // batch == XCD hint (stable)
    const int tile = bid >> 3;
    const int bx   = tile & 7;
    const int ty   = tile >> 3;
    const int X0   = bx * TXI;
    const int Y0   = ty * TYI;

    const bool interior = (bx > 0) & (bx < 7) & (ty > 0) & (ty < 15);

    if (interior) {
#if HAVE_GLDS
#pragma unroll
        for (int r = 0; r < 7; ++r) {
            const int chunk = r * 4 + wid;            // uniform per wave
            if (chunk < NCHUNK) {
                const int i   = chunk * 64 + lane;    // 0..1727
                const int row = i / SX;
                const int col = i - row * SX;
                const int gy  = Y0 - HALO + row;
                const int gx  = X0 - HALO + col;
                const half8* gp = g_cl + ((size_t)b * HH + gy) * WW + gx;
                GLOAD_LDS16(gp, (char*)g_lds8 + (size_t)chunk * 1024);
            }
        }
#else
        for (int i = t; i < NST; i += 256) {
            const int row = i / SX;
            const int col = i - row * SX;
            g_lds8[i] = g_cl[((size_t)b * HH + (Y0 - HALO + row)) * WW +
                             (X0 - HALO + col)];
        }
#endif
    } else {
        for (int i = t; i < NST; i += 256) {
            const int row = i / SX;
            const int col = i - row * SX;
            const int gy  = Y0 - HALO + row;
            const int gx  = X0 - HALO + col;
            half8 h;
#pragma unroll
            for (int c = 0; c < 8; ++c) h[c] = (_Float16)0.0f;
            if ((unsigned)gy < HH && (unsigned)gx < WW)
                h = g_cl[((size_t)b * HH + gy) * WW + gx];
            g_lds8[i] = h;
        }
    }

    // ---- per-thread pixel strip ----
    const int col = t % CW;               // 0..69
    const int grp = t / CW;               // 0..2 compute, 3 mostly idle
    const int sxc = 1 + col;
    const int syB = 1 + grp * RPT;

    unsigned vmask = 0;
#pragma unroll
    for (int k = 0; k < RPT; ++k) {
        const int sy = syB + k;
        const int gy = Y0 - HALO + sy;
        const int gx = X0 - HALO + sxc;
        if (grp < 3 && sy <= CYMAX && (unsigned)gy < HH && (unsigned)gx < WW)
            vmask |= (1u << k);
    }

    // ---- spv + invw loads (VMEM in flight under d staging + barrier) ----
    float spv[RPT];
    unsigned wv[RPT * 4];
#pragma unroll
    for (int k = 0; k < RPT; ++k) {
        spv[k] = 0.0f;
        wv[k * 4 + 0] = wv[k * 4 + 1] = wv[k * 4 + 2] = wv[k * 4 + 3] = 0u;
        if ((vmask >> k) & 1u) {
            const int gy = Y0 - HALO + syB + k;
            const int gx = X0 - HALO + sxc;
            const size_t q = ((size_t)b * HH + gy) * WW + gx;
            spv[k] = sparse[q];
            const uint4 iv = ((const uint4*)invw)[q];
            wv[k * 4 + 0] = iv.x; wv[k * 4 + 1] = iv.y;
            wv[k * 4 + 2] = iv.z; wv[k * 4 + 3] = iv.w;
        }
    }

    // ---- stage d ----
    if (interior) {
        for (int i = t; i < NST; i += 256) {
            const int row = i / SX;
            const int col2 = i - row * SX;
            d_lds[i] = src[((size_t)b * HH + (Y0 - HALO + row)) * WW +
                           (X0 - HALO + col2)];
        }
    } else {
        for (int i = t; i < NST; i += 256) {
            const int row = i / SX;
            const int col2 = i - row * SX;
            const int gy  = Y0 - HALO + row;
            const int gx  = X0 - HALO + col2;
            float dv = 0.0f;
            if ((unsigned)gy < HH && (unsigned)gx < WW)
                dv = src[((size_t)b * HH + gy) * WW + gx];
            d_lds[i] = dv;
        }
    }

    __syncthreads();   // drains g DMA (vmcnt) + d_lds writes (lgkmcnt)

    const uint4* gl = (const uint4*)g_lds8;

    float dnew[RPT];
#pragma unroll
    for (int k = 0; k < RPT; ++k) dnew[k] = 0.0f;

#pragma unroll 1
    for (int it = 0; it < HALO; ++it) {
        float rs[3][8];
        {
            const int r0 = (syB - 1 < SYTOP) ? (syB - 1) : SYTOP;
            const int r1 = (syB     < SYTOP) ? syB       : SYTOP;
#pragma unroll
            for (int c = 0; c < 8; ++c) { rs[0][c] = 0.0f; rs[1][c] = 0.0f; }
#pragma unroll
            for (int dx = 0; dx < 3; ++dx) {
                rowfma(rs[0], gl[r0 * SX + sxc - 1 + dx], d_lds[r0 * SX + sxc - 1 + dx]);
                rowfma(rs[1], gl[r1 * SX + sxc - 1 + dx], d_lds[r1 * SX + sxc - 1 + dx]);
            }
        }
#pragma unroll
        for (int k = 0; k < RPT; ++k) {
            const int rn = syB + 1 + k;
            const int rc = (rn < SYTOP) ? rn : SYTOP;
            float (&rsn)[8] = rs[(2 + k) % 3];
#pragma unroll
            for (int c = 0; c < 8; ++c) rsn[c] = 0.0f;
#pragma unroll
            for (int dx = 0; dx < 3; ++dx)
                rowfma(rsn, gl[rc * SX + sxc - 1 + dx], d_lds[rc * SX + sxc - 1 + dx]);

            const int ia = k % 3, ib = (k + 1) % 3, ic = (k + 2) % 3;
            float m = 0.0f;                       // candidates are >= 0
#pragma unroll
            for (int c = 0; c < 8; ++c) {
                const float s = rs[ia][c] + rs[ib][c] + rs[ic][c];
                const float v = (c & 1) ? mmixhi(wv[k * 4 + (c >> 1)], s)
                                        : mmixlo(wv[k * 4 + (c >> 1)], s);
                m = fmaxf(m, v);
            }
            dnew[k] = (spv[k] > 0.0f) ? spv[k] : m;
        }
        if (it < HALO - 1) {                      // last iter: regs only
            __syncthreads();                      // reads done
#pragma unroll
            for (int k = 0; k < RPT; ++k)
                if ((vmask >> k) & 1u) d_lds[(syB + k) * SX + sxc] = dnew[k];
            __syncthreads();                      // writes visible
        }
    }

    // ---- write inner 64x16 tile ----
#pragma unroll
    for (int k = 0; k < RPT; ++k) {
        const int sy = syB + k;
        if (((vmask >> k) & 1u) && sxc >= HALO && sxc < HALO + TXI &&
            sy >= HALO && sy < HALO + TYI) {
            const int gy = Y0 - HALO + sy;
            const int gx = X0 - HALO + sxc;
            dst[((size_t)b * HH + gy) * WW + gx] = dnew[k];
        }
    }
}

// -------------------------------------------------------------- launch ----
extern "C" void kernel_launch(void* const* d_in, const int* in_sizes, int n_in,
                              void* d_out, int out_size, void* d_ws, size_t ws_size,
                              hipStream_t stream) {
    const float* guidance = (const float*)d_in[0];
    const float* blur     = (const float*)d_in[1];
    const float* sparse   = (const float*)d_in[2];
    float* out = (float*)d_out;

    half8* g_cl   = (half8*)d_ws;                         // 16.78 MB
    half8* invw_g = g_cl + (size_t)NPIX;                  // 16.78 MB
    float* buf0   = (float*)(invw_g + (size_t)NPIX);      // 4 MB
    float* buf1   = buf0 + (size_t)NPIX;                  // 4 MB

    prep2_kernel<<<NBLK, 256, 0, stream>>>(guidance, blur, sparse,
                                           g_cl, invw_g, buf0);

    fused_kernel<<<NBLK, 256, 0, stream>>>(g_cl, invw_g, sparse, buf0, buf1);
    fused_kernel<<<NBLK, 256, 0, stream>>>(g_cl, invw_g, sparse, buf1, buf0);
    fused_kernel<<<NBLK, 256, 0, stream>>>(g_cl, invw_g, sparse, buf0, buf1);
    fused_kernel<<<NBLK, 256, 0, stream>>>(g_cl, invw_g, sparse, buf1, out);
}